// Round 3
// baseline (225.299 us; speedup 1.0000x reference)
//
#include <hip/hip_runtime.h>

#define NN 8000
#define FD 256
#define NEG_SLOPE 0.2f
#define BM 32
#define KT 32
#define JHALF (NN / 2)        // 4000
#define NS (JHALF / KT)       // 125

typedef __bf16 bf16;
typedef __bf16 bf16x8 __attribute__((ext_vector_type(8)));
typedef __bf16 bf16x2 __attribute__((ext_vector_type(2)));
typedef float f32x4 __attribute__((ext_vector_type(4)));

// ---------------- K1: H = X @ W^T + b -> Ht (bf16, transposed [f][i]) ----------------
__global__ __launch_bounds__(256) void k_linear(const float* __restrict__ X,
                                                const float* __restrict__ W,
                                                const float* __restrict__ b,
                                                bf16* __restrict__ Ht) {
    __shared__ float Xs[16][260];
    const int t = threadIdx.x;
    const int i0 = blockIdx.x * 16;
    #pragma unroll
    for (int r = 0; r < 16; ++r)
        Xs[r][t] = X[(size_t)(i0 + r) * FD + t];
    __syncthreads();
    const int f = t;
    float acc[16];
    const float bf_ = b[f];
    #pragma unroll
    for (int ii = 0; ii < 16; ++ii) acc[ii] = bf_;
    for (int k4 = 0; k4 < FD / 4; ++k4) {
        const float4 w4 = *(const float4*)&W[(size_t)f * FD + k4 * 4];
        #pragma unroll
        for (int ii = 0; ii < 16; ++ii) {
            const float4 x4 = *(const float4*)&Xs[ii][k4 * 4];
            acc[ii] += x4.x * w4.x + x4.y * w4.y + x4.z * w4.z + x4.w * w4.w;
        }
    }
    bf16x8 v0, v1;
    #pragma unroll
    for (int ii = 0; ii < 8; ++ii) { v0[ii] = (bf16)acc[ii]; v1[ii] = (bf16)acc[ii + 8]; }
    *(bf16x8*)&Ht[(size_t)f * NN + i0]     = v0;
    *(bf16x8*)&Ht[(size_t)f * NN + i0 + 8] = v1;
}

// ---------------- K2: hs = H@a_src + a_b, hd = H@a_dst (from Ht) ----------------
__global__ __launch_bounds__(256) void k_attn_vec(const bf16* __restrict__ Ht,
                                                  const float* __restrict__ a_src,
                                                  const float* __restrict__ a_dst,
                                                  const float* __restrict__ a_b,
                                                  float* __restrict__ hs,
                                                  float* __restrict__ hd) {
    __shared__ float psh[4][64], pdh[4][64];
    const int t = threadIdx.x;
    const int li = t & 63;
    const int q = t >> 6;
    const int i = blockIdx.x * 64 + li;
    float ps = 0.f, pd = 0.f;
    #pragma unroll 8
    for (int fi = 0; fi < 64; ++fi) {
        const int f = q * 64 + fi;
        const float h = (float)Ht[(size_t)f * NN + i];
        ps += h * a_src[f];
        pd += h * a_dst[f];
    }
    psh[q][li] = ps; pdh[q][li] = pd;
    __syncthreads();
    if (q == 0) {
        ps = psh[0][li] + psh[1][li] + psh[2][li] + psh[3][li];
        pd = pdh[0][li] + pdh[1][li] + pdh[2][li] + pdh[3][li];
        hs[i] = ps + a_b[0];
        hd[i] = pd;
    }
}

// ---------------- K3: fused weights + MFMA PV, split-j x2, atomic combine --------
// 512 thr (8 waves), BM=32 rows, KT=32 j per step. B-frags global->register
// (Ht is L2-resident); only the 32x32 weight tile goes through LDS (A operand,
// double-buffered, one raw barrier per step; B loads fly across the barrier).
__global__ __launch_bounds__(512, 4) void k_gat(const bf16* __restrict__ Ht,
                                                const int* __restrict__ adj,
                                                const float* __restrict__ hs,
                                                const float* __restrict__ hd,
                                                float* __restrict__ out,
                                                float* __restrict__ lg) {
    // Wt[buf][slot][row][8 bf16]: slot = k/8 (k within 32-tile), 16B units
    __shared__ __attribute__((aligned(16))) bf16 Wt[2][4 * 32 * 8];

    const int t  = threadIdx.x;
    const int l  = t & 63;
    const int wv = t >> 6;            // 0..7, owns cols [wv*32, wv*32+32)
    const int bid = blockIdx.x;
    const int ib = bid >> 1, jb = bid & 1;
    const int i0 = ib * BM;
    const int j0 = jb * JHALF;

    // weight-phase mapping: row = t>>4 (0..31), jp = t&15 -> j = j0+s*32+jp*2 (+1)
    const int row = t >> 4;
    const int jp  = t & 15;
    const float hsv = hs[i0 + row];
    // write slot = (jp*2)>>3 = jp>>2, elem offset (jp*2)&7 = (jp&3)*2
    bf16* const wtw[2] = {
        &Wt[0][(((jp >> 2) * 32) + row) * 8 + (jp & 3) * 2],
        &Wt[1][(((jp >> 2) * 32) + row) * 8 + (jp & 3) * 2]};

    // MFMA mapping
    const int al = l & 15, asl = l >> 4;

    const int* adjp = adj + (size_t)(i0 + row) * NN + j0 + jp * 2;
    const float* hdp = hd + j0 + jp * 2;
    const bf16* bp0 = Ht + (size_t)(wv * 32 + al) * NN + j0 + asl * 8;
    const bf16* bp1 = bp0 + (size_t)16 * NN;

    f32x4 acc00 = {0.f, 0.f, 0.f, 0.f}, acc01 = acc00, acc10 = acc00, acc11 = acc00;
    float lsum = 0.f;

    int2   adjc = *(const int2*)adjp;
    float2 hdc  = *(const float2*)hdp;

    #pragma unroll 1
    for (int s = 0; s < NS; ++s) {
        const int cur = s & 1;
        int2 adjn = {0, 0};
        float2 hdn = {0.f, 0.f};
        if (s + 1 < NS) {
            adjn = *(const int2*)(adjp + (size_t)(s + 1) * KT);
            hdn  = *(const float2*)(hdp + (size_t)(s + 1) * KT);
        }
        // issue B loads early; they stay in flight across the barrier
        const bf16x8 b0 = *(const bf16x8*)(bp0 + (size_t)s * KT);
        const bf16x8 b1 = *(const bf16x8*)(bp1 + (size_t)s * KT);

        // weight phase (2 w's per thread)
        float e0 = hsv + hdc.x; e0 = e0 >= 0.f ? e0 : NEG_SLOPE * e0;
        float e1 = hsv + hdc.y; e1 = e1 >= 0.f ? e1 : NEG_SLOPE * e1;
        const float w0 = adjc.x ? __expf(e0) : 0.f;
        const float w1 = adjc.y ? __expf(e1) : 0.f;
        lsum += w0 + w1;
        bf16x2 wpk; wpk[0] = (bf16)w0; wpk[1] = (bf16)w1;
        *(bf16x2*)wtw[cur] = wpk;

        asm volatile("s_waitcnt lgkmcnt(0)" ::: "memory");  // Wt write visible
        __builtin_amdgcn_s_barrier();                       // vmcnt NOT drained
        asm volatile("" ::: "memory");

        const bf16* wb = Wt[cur];
        const bf16x8 a0 = *(const bf16x8*)&wb[(asl * 32 + al) * 8];
        const bf16x8 a1 = *(const bf16x8*)&wb[(asl * 32 + 16 + al) * 8];
        acc00 = __builtin_amdgcn_mfma_f32_16x16x32_bf16(a0, b0, acc00, 0, 0, 0);
        acc01 = __builtin_amdgcn_mfma_f32_16x16x32_bf16(a0, b1, acc01, 0, 0, 0);
        acc10 = __builtin_amdgcn_mfma_f32_16x16x32_bf16(a1, b0, acc10, 0, 0, 0);
        acc11 = __builtin_amdgcn_mfma_f32_16x16x32_bf16(a1, b1, acc11, 0, 0, 0);

        adjc = adjn; hdc = hdn;
    }

    // row-sum partials: reduce across the 16 threads (l&15) sharing a row
    lsum += __shfl_xor(lsum, 1);
    lsum += __shfl_xor(lsum, 2);
    lsum += __shfl_xor(lsum, 4);
    lsum += __shfl_xor(lsum, 8);
    if ((l & 15) == 0) atomicAdd(&lg[i0 + row], lsum);

    // unnormalized numerator: exactly 2 atomic contributions per element
    #pragma unroll
    for (int g = 0; g < 4; ++g) {
        const int r0 = asl * 4 + g;
        atomicAdd(&out[(size_t)(i0 + r0) * FD + wv * 32 + al],           acc00[g]);
        atomicAdd(&out[(size_t)(i0 + r0) * FD + wv * 32 + 16 + al],      acc01[g]);
        atomicAdd(&out[(size_t)(i0 + 16 + r0) * FD + wv * 32 + al],      acc10[g]);
        atomicAdd(&out[(size_t)(i0 + 16 + r0) * FD + wv * 32 + 16 + al], acc11[g]);
    }
}

// ---------------- K4: normalize by row sums ----------------
__global__ __launch_bounds__(256) void k_norm(float* __restrict__ out,
                                              const float* __restrict__ lg) {
    const int i = blockIdx.x;
    const float rinv = 1.0f / lg[i];
    out[(size_t)i * FD + threadIdx.x] *= rinv;
}

extern "C" void kernel_launch(void* const* d_in, const int* in_sizes, int n_in,
                              void* d_out, int out_size, void* d_ws, size_t ws_size,
                              hipStream_t stream) {
    const float* X     = (const float*)d_in[0];
    const int*   adj   = (const int*)d_in[1];
    const float* Ww    = (const float*)d_in[2];
    const float* Wb    = (const float*)d_in[3];
    const float* a_src = (const float*)d_in[4];
    const float* a_dst = (const float*)d_in[5];
    const float* a_b   = (const float*)d_in[6];
    float* out = (float*)d_out;

    bf16*  Ht = (bf16*)d_ws;                                  // 4.096 MB
    float* hs = (float*)((char*)d_ws + (size_t)FD * NN * sizeof(bf16));
    float* hd = hs + NN;
    float* lg = hd + NN;

    hipMemsetAsync(out, 0, (size_t)NN * FD * sizeof(float), stream);
    hipMemsetAsync(lg, 0, NN * sizeof(float), stream);

    k_linear<<<NN / 16, 256, 0, stream>>>(X, Ww, Wb, Ht);
    k_attn_vec<<<NN / 64, 256, 0, stream>>>(Ht, a_src, a_dst, a_b, hs, hd);
    k_gat<<<(NN / BM) * 2, 512, 0, stream>>>(Ht, adj, hs, hd, out, lg);
    k_norm<<<NN, 256, 0, stream>>>(out, lg);
}